// Round 19
// baseline (243.576 us; speedup 1.0000x reference)
//
#include <hip/hip_runtime.h>
#include <hip/hip_fp16.h>
#include <math.h>

#define T_DIM 2048
#define TP_DIM 2052                  // padded t rows: tp = t + 2, 2 pad each side
#define K_DIM 17
#define HID   64
#define B_DIM 32

typedef short s16x8 __attribute__((ext_vector_type(8)));
typedef unsigned u32x2 __attribute__((ext_vector_type(2)));
typedef float f32x4 __attribute__((ext_vector_type(4)));
typedef _Float16 f16x2 __attribute__((ext_vector_type(2)));

// packed f32 pair -> f16 pair (1 instruction: v_cvt_pkrtz_f16_f32)
__device__ __forceinline__ unsigned pkh(float lo, float hi) {
    return __builtin_bit_cast(unsigned, __builtin_amdgcn_cvt_pkrtz(lo, hi));
}
__device__ __forceinline__ f16x2 u2h(unsigned v) {
    return __builtin_bit_cast(f16x2, v);
}
__device__ __forceinline__ unsigned h2u(f16x2 v) {
    return __builtin_bit_cast(unsigned, v);
}
__device__ __forceinline__ short f2h(float f) {          // cold path
    _Float16 h = (_Float16)f;
    return __builtin_bit_cast(short, h);
}

// COCO skeleton sparsity: column-v nonzeros of adj (incl. self).
static constexpr int NBR_PTR[18] = {0,3,6,9,11,13,17,21,24,27,29,31,34,37,40,43,45,47};
static constexpr int NBR_K[47] = {
    0,1,2,  0,1,3,  0,2,4,  1,3,  2,4,
    5,6,7,11,  5,6,8,12,  5,7,9,  6,8,10,  7,9,  8,10,
    5,11,13,  6,12,14,  11,13,15,  12,14,16,  13,15,  14,16 };
__device__ const int d_NBR_PTR[18] = {0,3,6,9,11,13,17,21,24,27,29,31,34,37,40,43,45,47};
__device__ const int d_NBR_K[47] = {
    0,1,2,  0,1,3,  0,2,4,  1,3,  2,4,
    5,6,7,11,  5,6,8,12,  5,7,9,  6,8,10,  7,9,  8,10,
    5,11,13,  6,12,14,  11,13,15,  12,14,16,  13,15,  14,16 };

// ---------------------------------------------------------------------------
// Fold GCN channel-mix into temporal conv weights (f16) — ORIGINAL 64-block
// version.  Extra duty: zero y2's 4 pad t-rows per batch.
//   effT0[o][k32]  k = dt*8+cin (cin<3, dt<3), rest 0    (block1, K=32)
//   effT12[blk][o][dt*64+c]                              (blocks 2,3, K=192)
//   bnc[blk*64+o] = s/sqrt(v+eps);  bnc[192+blk*64+o] = b - m*inv
// ---------------------------------------------------------------------------
__global__ void fold_weights_kernel(
    const float* __restrict__ gw0, const float* __restrict__ gw1,
    const float* __restrict__ gw2, const float* __restrict__ tcn,
    const float* __restrict__ bns, const float* __restrict__ bnb,
    const float* __restrict__ bnm, const float* __restrict__ bnv,
    short* __restrict__ effT0, short* __restrict__ effT12,
    float* __restrict__ bnc, short* __restrict__ y2, int cb)
{
    int tid = blockIdx.x * blockDim.x + threadIdx.x;
    int stride = gridDim.x * blockDim.x;
    for (int idx = tid; idx < 2048; idx += stride) {
        int o = idx >> 5, k = idx & 31, dt = k >> 3, cin = k & 7;
        float s = 0.f;
        if (dt < 3 && cin < 3)
            for (int m = 0; m < 64; m++)
                s += gw0[cin * 64 + m] * tcn[(o * 64 + m) * 3 + dt];
        effT0[idx] = f2h(s);
    }
    for (int idx = tid; idx < 24576; idx += stride) {
        int blk = idx / 12288;
        int r = idx - blk * 12288;
        int o = r / 192, k = r - o * 192, dt = k >> 6, c = k & 63;
        const float* gw = blk ? gw2 : gw1;
        const float* tw = tcn + (size_t)(blk + 1) * 64 * 64 * 3;
        float s = 0.f;
        for (int m = 0; m < 64; m++)
            s += gw[c * 64 + m] * tw[(o * 64 + m) * 3 + dt];
        effT12[idx] = f2h(s);
    }
    for (int i = tid; i < 192; i += stride) {
        float inv = bns[i] * rsqrtf(bnv[i] + 1e-5f);
        bnc[i] = inv;
        bnc[192 + i] = bnb[i] - bnm[i] * inv;
    }
    // zero y2 pad rows: tp in {0,1,2050,2051}, 17*64 shorts each, cb batches
    const int zn = cb * 4 * 1088;
    for (int z = tid; z < zn; z += stride) {
        int bb = z / (4 * 1088);
        int rr = z - bb * 4 * 1088;
        int pi = rr / 1088;
        int ci = rr - pi * 1088;
        int tp = (pi < 2) ? pi : (2048 + pi);
        y2[((size_t)(bb * TP_DIM + tp) * K_DIM) * 64 + ci] = 0;
    }
}

// ---------------------------------------------------------------------------
// Kernel A: blocks 1+2 fused, f16 pipeline — PREMIX ELIMINATED ALGEBRAICALLY.
// Adjacency commutes with the channel/temporal GEMM (adj acts on k; effT0
// on (cin,dt)): GEMM1 consumes RAW x (3 contiguous floats/lane, no barrier
// before it, OOB taps zero-padded in the B-frag), stores raw z1 in ybuf;
// then mix1 (clone of mix2 pattern) applies the sparse k->j mix + BN + ReLU
// + invalid-t zeroing IN-PLACE.  Block2 unchanged.  (256,4).
// ---------------------------------------------------------------------------
__global__ __launch_bounds__(256, 4) void stgcn_ab_kernel(
    const float* __restrict__ x, const float* __restrict__ adj,
    const short* __restrict__ effT0, const short* __restrict__ effT12,
    const float* __restrict__ bnc, short* __restrict__ y2)
{
    __shared__ unsigned adj_h[289];                    // f16x2 broadcast pairs
    __shared__ __align__(16) short ybuf[170 * 72];     // 24480 B

    const int tid = threadIdx.x;
    const int b = blockIdx.y;
    const int t0 = blockIdx.x * 8;
    const int lane = tid & 63, wave = tid >> 6;
    const int col = lane & 15, kgrp = lane >> 4;

    for (int i = tid; i < 289; i += 256) {
        float w = adj[i];
        adj_h[i] = pkh(w, w);
    }
    // weight A-frags (m-tile per wave: o = wave*16 + col)
    s16x8 af1 = *(const s16x8*)(effT0 + (wave * 16 + col) * 32 + kgrp * 8);
    s16x8 af2[6];
    #pragma unroll
    for (int kk = 0; kk < 6; kk++)
        af2[kk] = *(const s16x8*)(effT12 +
            (wave * 16 + col) * 192 + kk * 32 + kgrp * 8);

    // ---- GEMM1: 170 rows (11 tiles), K=32; B = RAW x (contiguous 12 B /
    //      lane, dt = kgrp, zero-pad OOB taps); raw z1 -> ybuf.  NO barrier
    //      before this loop — global reads overlap the adj_h stores. ----
    for (int tile = 0; tile < 11; tile++) {
        const int r = tile * 16 + col;
        const int me = r < 170 ? r : 169;
        const int s = (me * 241) >> 12;          // me/17
        const int k = me - s * 17;               // input keypoint
        const int tt = t0 - 2 + s + kgrp;        // tap time = t + (dt-1)
        int4 bz = {0, 0, 0, 0};
        if (kgrp < 3 && tt >= 0 && tt < T_DIM) {
            const float* xp = x + ((size_t)b * T_DIM + tt) * 51 + k * 3;
            bz.x = (int)pkh(xp[0], xp[1]);
            bz.y = (int)pkh(xp[2], 0.f);
        }
        s16x8 bfr = __builtin_bit_cast(s16x8, bz);
        f32x4 acc = __builtin_amdgcn_mfma_f32_16x16x32_f16(
            af1, bfr, (f32x4){0.f, 0.f, 0.f, 0.f}, 0, 0, 0);
        if (r < 170) {
            u32x2 st;
            st[0] = pkh(acc[0], acc[1]);
            st[1] = pkh(acc[2], acc[3]);
            *(u32x2*)&ybuf[r * 72 + wave * 16 + kgrp * 4] = st;
        }
    }
    __syncthreads();

    // ---- mix1 (packed f16, in-place): y1 = valid_t ? relu(mix_k(z1)*inv +
    //      shift) : 0.  10 t-rows x 32 o-pairs = 320 items.  Each item
    //      reads exactly the (17 rows x its column) cells it writes. ----
    for (int i = tid; i < 320; i += 256) {
        const int tl = i >> 5, o0 = (i & 31) * 2;
        const f16x2 inv2 = u2h(pkh(bnc[o0], bnc[o0 + 1]));
        const f16x2 sh2  = u2h(pkh(bnc[192 + o0], bnc[192 + o0 + 1]));
        const f16x2 zero = u2h(0u);
        f16x2 zk[17];
        #pragma unroll
        for (int k = 0; k < 17; k++)
            zk[k] = u2h(*(const unsigned*)&ybuf[(tl * 17 + k) * 72 + o0]);
        const int t = t0 - 1 + tl;
        const bool valid = (t >= 0) && (t < T_DIM);
        #pragma unroll
        for (int v = 0; v < 17; v++) {
            f16x2 g = zero;
            #pragma unroll
            for (int e = NBR_PTR[v]; e < NBR_PTR[v + 1]; e++) {
                int k = NBR_K[e];
                g = u2h(adj_h[k * 17 + v]) * zk[k] + g;
            }
            f16x2 val = __builtin_elementwise_max(g * inv2 + sh2, zero);
            *(unsigned*)&ybuf[(tl * 17 + v) * 72 + o0] =
                valid ? h2u(val) : 0u;
        }
    }
    __syncthreads();

    // ---- GEMM2: 136 rows (9 tiles), K=192, acc in regs ----
    f32x4 acc2[9];
    #pragma unroll
    for (int t2 = 0; t2 < 9; t2++) acc2[t2] = (f32x4){0.f, 0.f, 0.f, 0.f};
    #pragma unroll
    for (int kk = 0; kk < 6; kk++) {
        #pragma unroll
        for (int t2 = 0; t2 < 9; t2++) {
            const int r = t2 * 16 + col;
            const int me = r < 136 ? r : 135;
            s16x8 bfr = *(const s16x8*)&ybuf[
                (me + 17 * (kk >> 1)) * 72 + (kk & 1) * 32 + kgrp * 8];
            acc2[t2] = __builtin_amdgcn_mfma_f32_16x16x32_f16(
                af2[kk], bfr, acc2[t2], 0, 0, 0);
        }
    }
    // residual preload (y1 rows 17..152) into regs before overwrite
    unsigned rv[17];
    {
        const int tl = tid >> 5, o0 = (tid & 31) * 2;
        #pragma unroll
        for (int v = 0; v < 17; v++)
            rv[v] = *(const unsigned*)&ybuf[((tl + 1) * 17 + v) * 72 + o0];
    }
    __syncthreads();

    // ---- z2 -> ybuf rows 0..135 ----
    #pragma unroll
    for (int t2 = 0; t2 < 9; t2++) {
        const int r = t2 * 16 + col;
        if (r < 136) {
            u32x2 st;
            st[0] = pkh(acc2[t2][0], acc2[t2][1]);
            st[1] = pkh(acc2[t2][2], acc2[t2][3]);
            *(u32x2*)&ybuf[r * 72 + wave * 16 + kgrp * 4] = st;
        }
    }
    __syncthreads();

    // ---- mix2 (packed f16) + residual + coalesced y2 store (tp = t+2) ----
    {
        const int tl = tid >> 5, o0 = (tid & 31) * 2;
        const f16x2 inv2 = u2h(pkh(bnc[64 + o0], bnc[64 + o0 + 1]));
        const f16x2 sh2  = u2h(pkh(bnc[256 + o0], bnc[256 + o0 + 1]));
        const f16x2 zero = u2h(0u);
        f16x2 zk[17];
        #pragma unroll
        for (int k = 0; k < 17; k++)
            zk[k] = u2h(*(const unsigned*)&ybuf[(tl * 17 + k) * 72 + o0]);
        const size_t gout = ((size_t)b * TP_DIM + t0 + tl + 2) * K_DIM * 64;
        #pragma unroll
        for (int v = 0; v < 17; v++) {
            f16x2 g = zero;
            #pragma unroll
            for (int e = NBR_PTR[v]; e < NBR_PTR[v + 1]; e++) {
                int k = NBR_K[e];
                g = u2h(adj_h[k * 17 + v]) * zk[k] + g;
            }
            f16x2 val = __builtin_elementwise_max(g * inv2 + sh2, zero);
            val = val + u2h(rv[v]);
            *(unsigned*)&y2[gout + (size_t)v * 64 + o0] = h2u(val);
        }
    }
}

// ---------------------------------------------------------------------------
// Kernel B: block 3 (DIL=2) + pool, f16 pipeline.  Branch-free stage,
// GEMM3 acc regs, packed residual pre-sum, z3 overwrite, packed mix3 + pool.
// pr aliased into dead ybuf tail.  (256,4).
// ---------------------------------------------------------------------------
__global__ __launch_bounds__(256, 4) void stgcn_c_kernel(
    const short* __restrict__ y2, const float* __restrict__ adj,
    const short* __restrict__ effW3, const float* __restrict__ bnc,
    float* __restrict__ part, int b0)
{
    __shared__ unsigned adj_h[289];
    __shared__ __align__(16) short ybuf[204 * 72];     // 29376 B

    float* pr = (float*)&ybuf[136 * 72];   // alias: rows 136.. free at pool time

    const int tid = threadIdx.x;
    const int b = blockIdx.y;
    const int t0 = blockIdx.x * 8;
    const int lane = tid & 63, wave = tid >> 6;
    const int col = lane & 15, kgrp = lane >> 4;

    for (int i = tid; i < 289; i += 256) {
        float w = adj[i];
        adj_h[i] = pkh(w, w);
    }
    s16x8 af3[6];
    #pragma unroll
    for (int kk = 0; kk < 6; kk++)
        af3[kk] = *(const s16x8*)(effW3 +
            (wave * 16 + col) * 192 + kk * 32 + kgrp * 8);

    // branch-free coalesced stage: 204 rows (tp = t0 .. t0+11)
    {
        const short* base = y2 + ((size_t)b * TP_DIM + t0) * K_DIM * 64;
        for (int idx = tid; idx < 1632; idx += 256) {
            const int row = idx >> 3, c = idx & 7;
            *(s16x8*)&ybuf[row * 72 + c * 8] =
                *(const s16x8*)(base + (size_t)row * 64 + c * 8);
        }
    }
    __syncthreads();

    // ---- GEMM3: 136 rows (9 tiles), K=192, DIL=2, acc in regs ----
    f32x4 acc3[9];
    #pragma unroll
    for (int t3 = 0; t3 < 9; t3++) acc3[t3] = (f32x4){0.f, 0.f, 0.f, 0.f};
    #pragma unroll
    for (int kk = 0; kk < 6; kk++) {
        #pragma unroll
        for (int t3 = 0; t3 < 9; t3++) {
            const int r = t3 * 16 + col;
            const int me = r < 136 ? r : 135;
            s16x8 bfr = *(const s16x8*)&ybuf[
                (me + 34 * (kk >> 1)) * 72 + (kk & 1) * 32 + kgrp * 8];
            acc3[t3] = __builtin_amdgcn_mfma_f32_16x16x32_f16(
                af3[kk], bfr, acc3[t3], 0, 0, 0);
        }
    }
    // residual pre-sum (rows 34..169 = y2[t0..t0+7]), packed f16
    f16x2 rs = u2h(0u);
    {
        const int tl = tid >> 5, o0 = (tid & 31) * 2;
        #pragma unroll
        for (int v = 0; v < 17; v++)
            rs = rs + u2h(*(const unsigned*)&ybuf[((tl + 2) * 17 + v) * 72 + o0]);
    }
    __syncthreads();

    // ---- z3 -> ybuf rows 0..135 ----
    #pragma unroll
    for (int t3 = 0; t3 < 9; t3++) {
        const int r = t3 * 16 + col;
        if (r < 136) {
            u32x2 st;
            st[0] = pkh(acc3[t3][0], acc3[t3][1]);
            st[1] = pkh(acc3[t3][2], acc3[t3][3]);
            *(u32x2*)&ybuf[r * 72 + wave * 16 + kgrp * 4] = st;
        }
    }
    __syncthreads();

    // ---- mix3 (packed f16) + pool ----
    {
        const int tl = tid >> 5, o0 = (tid & 31) * 2;
        const f16x2 inv2 = u2h(pkh(bnc[128 + o0], bnc[128 + o0 + 1]));
        const f16x2 sh2  = u2h(pkh(bnc[320 + o0], bnc[320 + o0 + 1]));
        const f16x2 zero = u2h(0u);
        f16x2 zk[17];
        #pragma unroll
        for (int k = 0; k < 17; k++)
            zk[k] = u2h(*(const unsigned*)&ybuf[(tl * 17 + k) * 72 + o0]);
        float ps0 = (float)rs[0], ps1 = (float)rs[1];
        #pragma unroll
        for (int v = 0; v < 17; v++) {
            f16x2 g = zero;
            #pragma unroll
            for (int e = NBR_PTR[v]; e < NBR_PTR[v + 1]; e++) {
                int k = NBR_K[e];
                g = u2h(adj_h[k * 17 + v]) * zk[k] + g;
            }
            f16x2 val = __builtin_elementwise_max(g * inv2 + sh2, zero);
            ps0 += (float)val[0];
            ps1 += (float)val[1];
        }
        *(float2*)&pr[tl * 64 + o0] = make_float2(ps0, ps1);
    }
    __syncthreads();
    if (tid < 64) {
        float s = 0.f;
        #pragma unroll
        for (int i = 0; i < 8; i++) s += pr[i * 64 + tid];
        part[((size_t)(b0 + b) * 256 + blockIdx.x) * 64 + tid] = s;
    }
}

// ---------------------------------------------------------------------------
// Sum 256 partials per (b,c) with 256 threads, mean, LayerNorm, FC.
// ---------------------------------------------------------------------------
__global__ __launch_bounds__(256) void finish_kernel(
    const float* __restrict__ part, const float* __restrict__ ln_s,
    const float* __restrict__ ln_b, const float* __restrict__ fc_w,
    const float* __restrict__ fc_b, float* __restrict__ out)
{
    __shared__ float red[4][64];
    __shared__ float ns[64];
    const int b = blockIdx.x;
    const int g = threadIdx.x >> 6, c = threadIdx.x & 63;
    float s = 0.f;
    for (int j = 0; j < 64; j++)
        s += part[((size_t)b * 256 + g * 64 + j) * 64 + c];
    red[g][c] = s;
    __syncthreads();
    if (threadIdx.x < 64) {
        float feat = (red[0][c] + red[1][c] + red[2][c] + red[3][c])
                   / (float)(T_DIM * K_DIM);
        float m = feat;
        #pragma unroll
        for (int off = 32; off > 0; off >>= 1) m += __shfl_down(m, off);
        m = __shfl(m, 0) / 64.f;
        float d = feat - m;
        float v = d * d;
        #pragma unroll
        for (int off = 32; off > 0; off >>= 1) v += __shfl_down(v, off);
        v = __shfl(v, 0) / 64.f;
        ns[c] = d * rsqrtf(v + 1e-5f) * ln_s[c] + ln_b[c];
    }
    __syncthreads();
    if (threadIdx.x < 10) {
        float o = fc_b[threadIdx.x];
        for (int i = 0; i < 64; i++) o += ns[i] * fc_w[i * 10 + threadIdx.x];
        out[b * 10 + threadIdx.x] = o;
    }
}

// ---------------------------------------------------------------------------
extern "C" void kernel_launch(void* const* d_in, const int* in_sizes, int n_in,
                              void* d_out, int out_size, void* d_ws, size_t ws_size,
                              hipStream_t stream)
{
    const float* kpts = (const float*)d_in[0];
    const float* adj  = (const float*)d_in[1];
    const float* gw0  = (const float*)d_in[2];
    const float* gw1  = (const float*)d_in[3];
    const float* gw2  = (const float*)d_in[4];
    const float* tcn  = (const float*)d_in[5];
    const float* bns  = (const float*)d_in[6];
    const float* bnb  = (const float*)d_in[7];
    const float* bnm  = (const float*)d_in[8];
    const float* bnv  = (const float*)d_in[9];
    const float* lns  = (const float*)d_in[10];
    const float* lnb  = (const float*)d_in[11];
    const float* fcw  = (const float*)d_in[12];
    const float* fcb  = (const float*)d_in[13];
    float* out = (float*)d_out;

    // ws: bnc | part | effT0 | effT12 | y2 (padded)
    float* bnc  = (float*)d_ws;
    float* part = bnc + 384;
    short* effT0  = (short*)(part + (size_t)B_DIM * 256 * 64);
    short* effT12 = effT0 + 2048;
    short* y2     = effT12 + 24576;
    const size_t fixed_bytes = 384 * 4 + (size_t)B_DIM * 256 * 64 * 4
                             + 2048 * 2 + 24576 * 2;
    const size_t y2_per_b = (size_t)TP_DIM * K_DIM * 64 * 2;    // 4,465,152 B

    int cb = B_DIM;
    while (cb > 1 && fixed_bytes + (size_t)cb * y2_per_b > ws_size)
        cb >>= 1;

    fold_weights_kernel<<<64, 256, 0, stream>>>(gw0, gw1, gw2, tcn,
                                                bns, bnb, bnm, bnv,
                                                effT0, effT12, bnc, y2, cb);

    for (int b0 = 0; b0 < B_DIM; b0 += cb) {
        stgcn_ab_kernel<<<dim3(T_DIM / 8, cb), 256, 0, stream>>>(
            kpts + (size_t)b0 * T_DIM * K_DIM * 3, adj, effT0, effT12, bnc, y2);
        stgcn_c_kernel<<<dim3(T_DIM / 8, cb), 256, 0, stream>>>(
            y2, adj, effT12 + 12288, bnc, part, b0);
    }

    finish_kernel<<<B_DIM, 256, 0, stream>>>(part, lns, lnb, fcw, fcb, out);
}